// Round 5
// baseline (630.694 us; speedup 1.0000x reference)
//
#include <hip/hip_runtime.h>
#include <hip/hip_bf16.h>

#define NNODES 100000
#define NEDGES 1600000
#define ALPHA  0.2f
#define EPSV   1e-9f

// bucket sort geometry: 64 nodes per bucket
#define NBUCK 1563          // ceil(NNODES / 64)
#define CAP   1280          // Poisson(1024) + 8 sigma; guarded in attn

typedef __bf16 bf16x8 __attribute__((ext_vector_type(8)));
typedef float  f32x4  __attribute__((ext_vector_type(4)));
typedef unsigned short u16x8 __attribute__((ext_vector_type(8)));

// manual RNE f32 -> bf16 bits
static __device__ inline unsigned short f2bf(float f) {
    unsigned int u = __float_as_uint(f);
    unsigned int r = u + 0x7fff + ((u >> 16) & 1);
    return (unsigned short)(r >> 16);
}
static __device__ inline float bf2f(unsigned short v) {
    return __uint_as_float((unsigned int)v << 16);
}

// ---------------- init: zero bucket cursors + W [256][256] f32 -> Wt bf16 ----------
__global__ void k_init(const float* __restrict__ W, unsigned short* __restrict__ Wt,
                       int* __restrict__ cursor) {
    const int i = blockIdx.x * 256 + threadIdx.x;
    if (i < NBUCK) cursor[i] = 0;
    if (i < 65536) {
        const int n = i >> 8, k = i & 255;
        Wt[i] = f2bf(W[k * 256 + n]);
    }
}

// ---------------- bf16 MFMA GEMM: Wh = h @ W (verified round-0 form) ----------------
#define BM 128
#define BK 32
#define LSTRIDE 40
__global__ __launch_bounds__(256, 2) void k_gemm(const float* __restrict__ h,
                                                 const unsigned short* __restrict__ Wt,
                                                 unsigned short* __restrict__ Wh) {
    __shared__ __align__(16) unsigned short As[BM * LSTRIDE];
    __shared__ __align__(16) unsigned short Bs[256 * LSTRIDE];
    const int tid  = threadIdx.x;
    const int m0   = blockIdx.x * BM;
    const int wave = tid >> 6;
    const int lane = tid & 63;
    const int wm = (wave & 1) * 64;
    const int wn = (wave >> 1) * 128;
    const int fm = lane & 15;
    const int fq = lane >> 4;
    const int fk = fq * 8;

    f32x4 acc[4][8];
    const f32x4 z = {0.f, 0.f, 0.f, 0.f};
#pragma unroll
    for (int i = 0; i < 4; ++i)
#pragma unroll
        for (int j = 0; j < 8; ++j) acc[i][j] = z;

    const int arow = tid >> 1;
    const int acol = (tid & 1) * 16;
    const bool arow_ok = (m0 + arow) < NNODES;
    const float* hrow = h + (size_t)(m0 + arow) * 256 + acol;

    for (int kc = 0; kc < 256; kc += BK) {
        float4 a0, a1, a2, a3;
        if (arow_ok) {
            a0 = *(const float4*)(hrow + kc + 0);
            a1 = *(const float4*)(hrow + kc + 4);
            a2 = *(const float4*)(hrow + kc + 8);
            a3 = *(const float4*)(hrow + kc + 12);
        } else {
            a0 = a1 = a2 = a3 = make_float4(0.f, 0.f, 0.f, 0.f);
        }
        u16x8 bv[4];
#pragma unroll
        for (int q = 0; q < 4; ++q) {
            const int c = tid + 256 * q;
            const int n = c >> 2, koff = (c & 3) * 8;
            bv[q] = *(const u16x8*)(Wt + n * 256 + kc + koff);
        }
        __syncthreads();
        u16x8 p0, p1;
        p0[0]=f2bf(a0.x); p0[1]=f2bf(a0.y); p0[2]=f2bf(a0.z); p0[3]=f2bf(a0.w);
        p0[4]=f2bf(a1.x); p0[5]=f2bf(a1.y); p0[6]=f2bf(a1.z); p0[7]=f2bf(a1.w);
        p1[0]=f2bf(a2.x); p1[1]=f2bf(a2.y); p1[2]=f2bf(a2.z); p1[3]=f2bf(a2.w);
        p1[4]=f2bf(a3.x); p1[5]=f2bf(a3.y); p1[6]=f2bf(a3.z); p1[7]=f2bf(a3.w);
        *(u16x8*)&As[arow * LSTRIDE + acol]     = p0;
        *(u16x8*)&As[arow * LSTRIDE + acol + 8] = p1;
#pragma unroll
        for (int q = 0; q < 4; ++q) {
            const int c = tid + 256 * q;
            const int n = c >> 2, koff = (c & 3) * 8;
            *(u16x8*)&Bs[n * LSTRIDE + koff] = bv[q];
        }
        __syncthreads();
        bf16x8 af[4], bfr[8];
#pragma unroll
        for (int i = 0; i < 4; ++i)
            af[i] = __builtin_bit_cast(bf16x8,
                *(const u16x8*)&As[(wm + 16 * i + fm) * LSTRIDE + fk]);
#pragma unroll
        for (int j = 0; j < 8; ++j)
            bfr[j] = __builtin_bit_cast(bf16x8,
                *(const u16x8*)&Bs[(wn + 16 * j + fm) * LSTRIDE + fk]);
#pragma unroll
        for (int i = 0; i < 4; ++i)
#pragma unroll
            for (int j = 0; j < 8; ++j)
                acc[i][j] = __builtin_amdgcn_mfma_f32_16x16x32_bf16(af[i], bfr[j], acc[i][j], 0, 0, 0);
    }
#pragma unroll
    for (int i = 0; i < 4; ++i) {
#pragma unroll
        for (int r = 0; r < 4; ++r) {
            const int grow = m0 + wm + 16 * i + fq * 4 + r;
            if (grow < NNODES) {
                unsigned short* orow = Wh + (size_t)grow * 256 + wn + fm;
#pragma unroll
                for (int j = 0; j < 8; ++j)
                    orow[16 * j] = f2bf(acc[i][j][r]);
            }
        }
    }
}

// ---------------- attention + bucket scatter ----------------
// 4 lanes per edge (round-0 verified structure). Lane 0 of each quad computes
// exp(leakyrelu(dot)), claims a slot in src's bucket (1563 cursors), stores an
// 8B record: meta = dst | (local_node << 17), w bits.
__global__ __launch_bounds__(256) void k_attn_bucket(const float* __restrict__ label,
                                                     const int* __restrict__ src,
                                                     const int* __restrict__ dst,
                                                     int* __restrict__ cursor,
                                                     uint2* __restrict__ rec) {
    const int t = blockIdx.x * 256 + threadIdx.x;
    const int e = t >> 2;
    const int l4 = t & 3;
    if (e >= NEDGES) return;
    const int s = src[e], d = dst[e];
    const float4* ls = (const float4*)&label[s * 32 + l4 * 8];
    const float4* ld = (const float4*)&label[d * 32 + l4 * 8];
    const float4 a0 = ls[0], a1 = ls[1];
    const float4 b0 = ld[0], b1 = ld[1];
    float dot = a0.x * b0.x + a0.y * b0.y + a0.z * b0.z + a0.w * b0.w
              + a1.x * b1.x + a1.y * b1.y + a1.z * b1.z + a1.w * b1.w;
    dot += __shfl_xor(dot, 1);
    dot += __shfl_xor(dot, 2);
    if (l4 == 0) {
        const float lr = dot >= 0.f ? dot : ALPHA * dot;
        const float w = expf(lr);
        const int b = s >> 6;                 // bucket
        const int loc = s & 63;               // local node id within bucket
        const int pos = atomicAdd(&cursor[b], 1);
        if (pos < CAP)
            rec[b * CAP + pos] = make_uint2((unsigned)(d | (loc << 17)),
                                            __float_as_uint(w));
    }
}

// ---------------- fused local-sort + aggregation ----------------
// Block b owns nodes [b*64, b*64+64) and bucket region rec[b*CAP ..].
// Phase 1: count per local node (LDS). Phase 2: LDS Hillis-Steele scan.
// Phase 3: re-read bucket (L2-hot), scatter records into LDS mini-CSR srt[].
// Phase 4: round-0 verified gather loop, packs read from LDS instead of global.
__global__ __launch_bounds__(256) void k_agg(const unsigned short* __restrict__ Wh,
                                             const int* __restrict__ cursor,
                                             const uint2* __restrict__ rec,
                                             float* __restrict__ out) {
    __shared__ int cnt[64];
    __shared__ int sc[64];      // inclusive scan of cnt (preserved)
    __shared__ int cur[64];     // scatter cursors (mutates to end)
    __shared__ uint2 srt[CAP];  // bucket-local CSR: (dst, w_bits)

    const int b = blockIdx.x;
    const int tid = threadIdx.x;
    const int n0 = b * 64;
    const uint2* __restrict__ rbase = rec + (size_t)b * CAP;
    const int nb = min(cursor[b], CAP);

    if (tid < 64) cnt[tid] = 0;
    __syncthreads();
    // phase 1: count
    for (int i = tid; i < nb; i += 256) {
        const unsigned meta = rbase[i].x;
        atomicAdd(&cnt[meta >> 17], 1);
    }
    __syncthreads();
    // phase 2: inclusive scan over 64 entries
    if (tid < 64) sc[tid] = cnt[tid];
    __syncthreads();
    for (int o = 1; o < 64; o <<= 1) {
        int tv = 0;
        if (tid < 64 && tid >= o) tv = sc[tid - o];
        __syncthreads();
        if (tid < 64) sc[tid] += tv;
        __syncthreads();
    }
    if (tid < 64) cur[tid] = sc[tid] - cnt[tid];   // exclusive start
    __syncthreads();
    // phase 3: scatter into LDS mini-CSR (bucket region is L2-hot from phase 1)
    for (int i = tid; i < nb; i += 256) {
        const uint2 r = rbase[i];
        const int loc = r.x >> 17;
        const int p = atomicAdd(&cur[loc], 1);
        srt[p] = make_uint2(r.x & 0x1FFFFu, r.y);
    }
    __syncthreads();

    // phase 4: aggregation, 8 nodes per 256-thread group-round, 32 lanes/node
    const int sub = tid & 31;                      // owns channels [sub*8, +8)
    const unsigned short* __restrict__ Whc = Wh + sub * 8;
#pragma unroll 1
    for (int it = 0; it < 8; ++it) {
        const int nl = it * 8 + (tid >> 5);        // local node 0..63
        const int node = n0 + nl;
        const int re = sc[nl];
        const int rs = re - cnt[nl];
        float acc[8] = {0.f, 0.f, 0.f, 0.f, 0.f, 0.f, 0.f, 0.f};
        float wsum = 0.f;
        int i = rs;
        for (; i + 4 <= re; i += 4) {
            const uint2 p0 = srt[i + 0];
            const uint2 p1 = srt[i + 1];
            const uint2 p2 = srt[i + 2];
            const uint2 p3 = srt[i + 3];
            const u16x8 v0 = *(const u16x8*)&Whc[(size_t)p0.x * 256];
            const u16x8 v1 = *(const u16x8*)&Whc[(size_t)p1.x * 256];
            const u16x8 v2 = *(const u16x8*)&Whc[(size_t)p2.x * 256];
            const u16x8 v3 = *(const u16x8*)&Whc[(size_t)p3.x * 256];
            const float w0 = __uint_as_float(p0.y), w1 = __uint_as_float(p1.y);
            const float w2 = __uint_as_float(p2.y), w3 = __uint_as_float(p3.y);
            wsum += (w0 + w1) + (w2 + w3);
#pragma unroll
            for (int c = 0; c < 8; ++c) {
                acc[c] = fmaf(w0, bf2f(v0[c]), acc[c]);
                acc[c] = fmaf(w1, bf2f(v1[c]), acc[c]);
                acc[c] = fmaf(w2, bf2f(v2[c]), acc[c]);
                acc[c] = fmaf(w3, bf2f(v3[c]), acc[c]);
            }
        }
        for (; i < re; ++i) {
            const uint2 p = srt[i];
            const u16x8 v = *(const u16x8*)&Whc[(size_t)p.x * 256];
            const float w = __uint_as_float(p.y);
            wsum += w;
#pragma unroll
            for (int c = 0; c < 8; ++c) acc[c] = fmaf(w, bf2f(v[c]), acc[c]);
        }
        if (node < NNODES) {
            const float inv = 1.f / fmaxf(wsum, EPSV);
            float4 o0 = make_float4(acc[0] * inv, acc[1] * inv, acc[2] * inv, acc[3] * inv);
            float4 o1 = make_float4(acc[4] * inv, acc[5] * inv, acc[6] * inv, acc[7] * inv);
            float* orow = out + (size_t)node * 256 + sub * 8;
            *(float4*)(orow + 0) = o0;
            *(float4*)(orow + 4) = o1;
        }
    }
}

extern "C" void kernel_launch(void* const* d_in, const int* in_sizes, int n_in,
                              void* d_out, int out_size, void* d_ws, size_t ws_size,
                              hipStream_t stream) {
    const float* h     = (const float*)d_in[0];   // [N,256]
    const float* label = (const float*)d_in[1];   // [N,32]
    const float* W     = (const float*)d_in[2];   // [256,256]
    const int*   adj   = (const int*)d_in[3];     // [2,E]
    const int* src = adj;
    const int* dst = adj + NEDGES;
    float* out = (float*)d_out;

    // workspace layout (bytes)
    char* ws = (char*)d_ws;
    unsigned short* Wh = (unsigned short*)(ws + 0);          // N*256*2  = 51,200,000
    unsigned short* Wt = (unsigned short*)(ws + 51200000);   // 256*256*2 = 131,072
    uint2* rec         = (uint2*)(ws + 51400000);            // NBUCK*CAP*8 = 16,005,120
    int*   cursor      = (int*)  (ws + 67500000);            // NBUCK*4 = 6,252

    k_init<<<256, 256, 0, stream>>>(W, Wt, cursor);
    k_gemm<<<(NNODES + BM - 1) / BM, 256, 0, stream>>>(h, Wt, Wh);
    k_attn_bucket<<<(4 * NEDGES + 255) / 256, 256, 0, stream>>>(label, src, dst,
                                                                cursor, rec);
    k_agg<<<NBUCK, 256, 0, stream>>>(Wh, cursor, rec, out);
}

// Round 6
// 419.715 us; speedup vs baseline: 1.5027x; 1.5027x over previous
//
#include <hip/hip_runtime.h>
#include <hip/hip_bf16.h>

#define NNODES 100000
#define NEDGES 1600000
#define ALPHA  0.2f
#define EPSV   1e-9f

typedef __bf16 bf16x8 __attribute__((ext_vector_type(8)));
typedef float  f32x4  __attribute__((ext_vector_type(4)));
typedef unsigned short u16x8 __attribute__((ext_vector_type(8)));

// manual RNE f32 -> bf16 bits
static __device__ inline unsigned short f2bf(float f) {
    unsigned int u = __float_as_uint(f);
    unsigned int r = u + 0x7fff + ((u >> 16) & 1);
    return (unsigned short)(r >> 16);
}
static __device__ inline float bf2f(unsigned short v) {
    return __uint_as_float((unsigned int)v << 16);
}

// ---------------- init: head sentinels + W [256][256] f32 -> Wt bf16 (transposed) --
__global__ void k_init(const float* __restrict__ W, unsigned short* __restrict__ Wt,
                       unsigned int* __restrict__ head) {
    const int i = blockIdx.x * 256 + threadIdx.x;
    if (i < NNODES) head[i] = 0xFFFFFFFFu;
    if (i < 65536) {
        const int n = i >> 8, k = i & 255;
        Wt[i] = f2bf(W[k * 256 + n]);
    }
}

// ---------------- bf16 MFMA GEMM: Wh = h @ W (verified round-0 form) ----------------
#define BM 128
#define BK 32
#define LSTRIDE 40
__global__ __launch_bounds__(256, 2) void k_gemm(const float* __restrict__ h,
                                                 const unsigned short* __restrict__ Wt,
                                                 unsigned short* __restrict__ Wh) {
    __shared__ __align__(16) unsigned short As[BM * LSTRIDE];
    __shared__ __align__(16) unsigned short Bs[256 * LSTRIDE];
    const int tid  = threadIdx.x;
    const int m0   = blockIdx.x * BM;
    const int wave = tid >> 6;
    const int lane = tid & 63;
    const int wm = (wave & 1) * 64;
    const int wn = (wave >> 1) * 128;
    const int fm = lane & 15;
    const int fq = lane >> 4;
    const int fk = fq * 8;

    f32x4 acc[4][8];
    const f32x4 z = {0.f, 0.f, 0.f, 0.f};
#pragma unroll
    for (int i = 0; i < 4; ++i)
#pragma unroll
        for (int j = 0; j < 8; ++j) acc[i][j] = z;

    const int arow = tid >> 1;
    const int acol = (tid & 1) * 16;
    const bool arow_ok = (m0 + arow) < NNODES;
    const float* hrow = h + (size_t)(m0 + arow) * 256 + acol;

    for (int kc = 0; kc < 256; kc += BK) {
        float4 a0, a1, a2, a3;
        if (arow_ok) {
            a0 = *(const float4*)(hrow + kc + 0);
            a1 = *(const float4*)(hrow + kc + 4);
            a2 = *(const float4*)(hrow + kc + 8);
            a3 = *(const float4*)(hrow + kc + 12);
        } else {
            a0 = a1 = a2 = a3 = make_float4(0.f, 0.f, 0.f, 0.f);
        }
        u16x8 bv[4];
#pragma unroll
        for (int q = 0; q < 4; ++q) {
            const int c = tid + 256 * q;
            const int n = c >> 2, koff = (c & 3) * 8;
            bv[q] = *(const u16x8*)(Wt + n * 256 + kc + koff);
        }
        __syncthreads();
        u16x8 p0, p1;
        p0[0]=f2bf(a0.x); p0[1]=f2bf(a0.y); p0[2]=f2bf(a0.z); p0[3]=f2bf(a0.w);
        p0[4]=f2bf(a1.x); p0[5]=f2bf(a1.y); p0[6]=f2bf(a1.z); p0[7]=f2bf(a1.w);
        p1[0]=f2bf(a2.x); p1[1]=f2bf(a2.y); p1[2]=f2bf(a2.z); p1[3]=f2bf(a2.w);
        p1[4]=f2bf(a3.x); p1[5]=f2bf(a3.y); p1[6]=f2bf(a3.z); p1[7]=f2bf(a3.w);
        *(u16x8*)&As[arow * LSTRIDE + acol]     = p0;
        *(u16x8*)&As[arow * LSTRIDE + acol + 8] = p1;
#pragma unroll
        for (int q = 0; q < 4; ++q) {
            const int c = tid + 256 * q;
            const int n = c >> 2, koff = (c & 3) * 8;
            *(u16x8*)&Bs[n * LSTRIDE + koff] = bv[q];
        }
        __syncthreads();
        bf16x8 af[4], bfr[8];
#pragma unroll
        for (int i = 0; i < 4; ++i)
            af[i] = __builtin_bit_cast(bf16x8,
                *(const u16x8*)&As[(wm + 16 * i + fm) * LSTRIDE + fk]);
#pragma unroll
        for (int j = 0; j < 8; ++j)
            bfr[j] = __builtin_bit_cast(bf16x8,
                *(const u16x8*)&Bs[(wn + 16 * j + fm) * LSTRIDE + fk]);
#pragma unroll
        for (int i = 0; i < 4; ++i)
#pragma unroll
            for (int j = 0; j < 8; ++j)
                acc[i][j] = __builtin_amdgcn_mfma_f32_16x16x32_bf16(af[i], bfr[j], acc[i][j], 0, 0, 0);
    }
#pragma unroll
    for (int i = 0; i < 4; ++i) {
#pragma unroll
        for (int r = 0; r < 4; ++r) {
            const int grow = m0 + wm + 16 * i + fq * 4 + r;
            if (grow < NNODES) {
                unsigned short* orow = Wh + (size_t)grow * 256 + wn + fm;
#pragma unroll
                for (int j = 0; j < 8; ++j)
                    orow[16 * j] = f2bf(acc[i][j][r]);
            }
        }
    }
}

// ---------------- attention + linked-list build ----------------
// Round-0 verified attn structure (4 lanes/edge, quad shuffle reduce).
// Lane 0 of each quad: w = exp(leakyrelu(dot)), then pushes edge e onto node
// src[e]'s list: head[s] <- e (atomicExch, 100K addresses = verified-OK
// contention), record = {next=old_head, dst, w_bits, pad} as one 16B store.
// Replaces count+scan1/2/3+scatter (the whole CSR sort) entirely.
__global__ __launch_bounds__(256) void k_attn_chain(const float* __restrict__ label,
                                                    const int* __restrict__ src,
                                                    const int* __restrict__ dst,
                                                    unsigned int* __restrict__ head,
                                                    uint4* __restrict__ rec) {
    const int t = blockIdx.x * 256 + threadIdx.x;
    const int e = t >> 2;            // edge id
    const int l4 = t & 3;            // lane within quad
    if (e >= NEDGES) return;
    const int s = src[e], d = dst[e];
    const float4* ls = (const float4*)&label[s * 32 + l4 * 8];
    const float4* ld = (const float4*)&label[d * 32 + l4 * 8];
    const float4 a0 = ls[0], a1 = ls[1];
    const float4 b0 = ld[0], b1 = ld[1];
    float dot = a0.x * b0.x + a0.y * b0.y + a0.z * b0.z + a0.w * b0.w
              + a1.x * b1.x + a1.y * b1.y + a1.z * b1.z + a1.w * b1.w;
    dot += __shfl_xor(dot, 1);
    dot += __shfl_xor(dot, 2);
    if (l4 == 0) {
        const float lr = dot >= 0.f ? dot : ALPHA * dot;
        const float w = expf(lr);
        const unsigned int old = atomicExch(&head[s], (unsigned int)e);
        rec[e] = make_uint4(old, (unsigned int)d, __float_as_uint(w), 0u);
    }
}

// ---------------- aggregation: chain walk, 32 lanes/node ----------------
// Per step: one broadcast 16B rec load (same addr across the 32 lanes -> single
// fetch), then the dependent 512B row gather (each lane 16B). Chain serialism is
// hidden by TLP: 12500 blocks, ~16K concurrent nodes keep ~8MB of gathers in
// flight (>> the ~2.4MB needed at ~4TB/s, 600ns).
__global__ __launch_bounds__(256) void k_aggregate(const unsigned short* __restrict__ Wh,
                                                   const unsigned int* __restrict__ head,
                                                   const uint4* __restrict__ rec,
                                                   float* __restrict__ out) {
    const int node = blockIdx.x * 8 + (threadIdx.x >> 5);
    if (node >= NNODES) return;
    const int sub = threadIdx.x & 31;      // owns channels [sub*8, sub*8+8)
    const unsigned short* __restrict__ Whc = Wh + sub * 8;
    float acc[8] = {0.f, 0.f, 0.f, 0.f, 0.f, 0.f, 0.f, 0.f};
    float wsum = 0.f;
    unsigned int cur = head[node];
    while (cur != 0xFFFFFFFFu) {
        const uint4 p = rec[cur];
        const u16x8 v = *(const u16x8*)&Whc[(size_t)p.y * 256];
        const float w = __uint_as_float(p.z);
        wsum += w;
#pragma unroll
        for (int c = 0; c < 8; ++c) acc[c] = fmaf(w, bf2f(v[c]), acc[c]);
        cur = p.x;
    }
    const float inv = 1.f / fmaxf(wsum, EPSV);
    float4 o0 = make_float4(acc[0] * inv, acc[1] * inv, acc[2] * inv, acc[3] * inv);
    float4 o1 = make_float4(acc[4] * inv, acc[5] * inv, acc[6] * inv, acc[7] * inv);
    float* orow = out + (size_t)node * 256 + sub * 8;
    *(float4*)(orow + 0) = o0;
    *(float4*)(orow + 4) = o1;
}

extern "C" void kernel_launch(void* const* d_in, const int* in_sizes, int n_in,
                              void* d_out, int out_size, void* d_ws, size_t ws_size,
                              hipStream_t stream) {
    const float* h     = (const float*)d_in[0];   // [N,256]
    const float* label = (const float*)d_in[1];   // [N,32]
    const float* W     = (const float*)d_in[2];   // [256,256]
    const int*   adj   = (const int*)d_in[3];     // [2,E]
    const int* src = adj;
    const int* dst = adj + NEDGES;
    float* out = (float*)d_out;

    // workspace layout (bytes)
    char* ws = (char*)d_ws;
    unsigned short* Wh   = (unsigned short*)(ws + 0);          // N*256*2  = 51,200,000
    unsigned short* Wt   = (unsigned short*)(ws + 51200000);   // 256*256*2 = 131,072
    uint4*        rec    = (uint4*)        (ws + 51400000);    // E*16 = 25,600,000
    unsigned int* head   = (unsigned int*) (ws + 77000000);    // N*4  = 400,000

    k_init<<<392, 256, 0, stream>>>(W, Wt, head);
    k_gemm<<<(NNODES + BM - 1) / BM, 256, 0, stream>>>(h, Wt, Wh);
    k_attn_chain<<<(4 * NEDGES + 255) / 256, 256, 0, stream>>>(label, src, dst, head, rec);
    k_aggregate<<<(NNODES + 7) / 8, 256, 0, stream>>>(Wh, head, rec, out);
}